// Round 8
// baseline (2129.224 us; speedup 1.0000x reference)
//
#include <hip/hip_runtime.h>
#include <hip/hip_bf16.h>

typedef float  f32x4_t  __attribute__((ext_vector_type(4)));

#define NB   4
#define NH   16
#define SEQ  2048
#define HD   64
#define BQ   64
#define BKV  64
#define KSTR 68   // fp32 LDS row stride (floats)

// masked score in base-2 domain: WHERE_CONST * log2(e) = -10000 * 1.4426950408889634
#define MASK2 (-14426.950408889634f)

__launch_bounds__(256, 1)
__global__ void fa_fwd(const float* __restrict__ qg,
                       const float* __restrict__ kg,
                       const float* __restrict__ vg,
                       float* __restrict__ outg) {
    __shared__ float kf[BKV * KSTR];   // K tile fp32 [kv][d]
    __shared__ float vf[BKV * KSTR];   // V tile fp32 [kv][d]

    const int tid = threadIdx.x;
    const int row = tid >> 2;   // q-row this thread owns (0..63)
    const int dq  = tid & 3;    // d-quarter this thread owns (16 d's)

    const int qt = (int)gridDim.x - 1 - (int)blockIdx.x;   // heavy blocks first
    const int bh = blockIdx.y;
    const int q0 = qt * BQ;

    const size_t base = (size_t)bh * SEQ * HD;
    const float* qp = qg + base;
    const float* kp = kg + base;
    const float* vp = vg + base;

    // ---- Q row segment fp32: Q[q0+row][dq*16 .. dq*16+15] ----
    float qv[16];
    {
        const f32x4_t* qr = (const f32x4_t*)(qp + (size_t)(q0 + row) * HD + dq * 16);
        #pragma unroll
        for (int u = 0; u < 4; ++u) {
            f32x4_t v4 = qr[u];
            qv[u * 4 + 0] = v4[0]; qv[u * 4 + 1] = v4[1];
            qv[u * 4 + 2] = v4[2]; qv[u * 4 + 3] = v4[3];
        }
    }

    // per-thread O slice: O[row][dq*16 + j]
    float o[16];
    #pragma unroll
    for (int j = 0; j < 16; ++j) o[j] = 0.0f;
    float m_my = MASK2;   // running row max (base-2 domain)
    float l_my = 0.0f;    // running row sum

    const float SCL2 = 0.125f * 1.44269504088896340736f;  // scale * log2(e)

    const int ntiles = qt + 1;
    for (int t = 0; t < ntiles; ++t) {
        const int kt0 = t * BKV;
        __syncthreads();   // previous readers done before overwrite

        // ---- stage K and V tiles as fp32 (float4 coalesced) ----
        #pragma unroll
        for (int it = 0; it < 4; ++it) {
            int idx = it * 256 + tid;       // 0..1023 = 64 rows x 16 float4-blocks
            int r0  = idx >> 4;
            int cb  = idx & 15;
            f32x4_t k4 = *(const f32x4_t*)(kp + (size_t)(kt0 + r0) * HD + cb * 4);
            f32x4_t v4 = *(const f32x4_t*)(vp + (size_t)(kt0 + r0) * HD + cb * 4);
            *(f32x4_t*)&kf[r0 * KSTR + cb * 4] = k4;
            *(f32x4_t*)&vf[r0 * KSTR + cb * 4] = v4;
        }
        __syncthreads();

        // ---- S partials: this thread's 16 d's, all 64 kv ----
        float s[64];
        #pragma unroll
        for (int i = 0; i < 64; ++i) {
            const float* kr = &kf[i * KSTR + dq * 16];
            float acc = 0.0f;
            #pragma unroll
            for (int j = 0; j < 16; ++j) acc += qv[j] * kr[j];
            s[i] = acc;
        }
        // reduce the 4 d-quarters (lanes differing in bits 0..1 share a row)
        #pragma unroll
        for (int i = 0; i < 64; ++i) {
            s[i] += __shfl_xor(s[i], 1);
            s[i] += __shfl_xor(s[i], 2);
        }

        // ---- mask + online softmax, fully per-thread ----
        const bool diag = (kt0 == q0);
        float vmax = MASK2;
        #pragma unroll
        for (int i = 0; i < 64; ++i) {
            float x = s[i] * SCL2;
            if (diag && i > row) x = MASK2;   // reference-exact WHERE_CONST (base-2)
            s[i] = x;
            vmax = fmaxf(vmax, x);
        }
        const float mn    = fmaxf(m_my, vmax);
        const float alpha = __builtin_amdgcn_exp2f(fminf(m_my - mn, 0.0f));
        m_my = mn;
        float rs = 0.0f;
        #pragma unroll
        for (int i = 0; i < 64; ++i) {
            float p = __builtin_amdgcn_exp2f(fminf(s[i] - mn, 0.0f));
            s[i] = p;   // P stays in registers (fp32, reference-faithful)
            rs += p;
        }
        l_my = l_my * alpha + rs;

        // ---- O rescale + PV, fully per-thread ----
        #pragma unroll
        for (int j = 0; j < 16; ++j) o[j] *= alpha;
        for (int i = 0; i < 64; ++i) {
            const float p = s[i];
            const float* vr = &vf[i * KSTR + dq * 16];
            #pragma unroll
            for (int j = 0; j < 16; ++j) o[j] += p * vr[j];
        }
    }

    // ---- epilogue: O / l, FP32 store (reference output dtype) ----
    const int b = bh >> 4;
    const int h = bh & 15;
    const float inv_l = 1.0f / fmaxf(l_my, 1e-30f);
    float* op = outg + ((size_t)b * SEQ + (q0 + row)) * (NH * HD) + h * HD + dq * 16;
    #pragma unroll
    for (int u = 0; u < 4; ++u) {
        f32x4_t w;
        #pragma unroll
        for (int j = 0; j < 4; ++j) {
            float val = o[u * 4 + j] * inv_l;
            unsigned bits = __builtin_bit_cast(unsigned, val);
            if ((bits & 0x7F800000u) == 0x7F800000u) val = 0.0f;  // scrub inf/NaN
            w[j] = val;
        }
        *(f32x4_t*)(op + u * 4) = w;
    }
}

extern "C" void kernel_launch(void* const* d_in, const int* in_sizes, int n_in,
                              void* d_out, int out_size, void* d_ws, size_t ws_size,
                              hipStream_t stream) {
    const float* q = (const float*)d_in[0];
    const float* k = (const float*)d_in[1];
    const float* v = (const float*)d_in[2];
    float* out = (float*)d_out;
    dim3 grid(SEQ / BQ, NB * NH);
    fa_fwd<<<grid, 256, 0, stream>>>(q, k, v, out);
}

// Round 9
// 412.590 us; speedup vs baseline: 5.1606x; 5.1606x over previous
//
#include <hip/hip_runtime.h>
#include <hip/hip_bf16.h>

typedef __bf16 bf16x8_t __attribute__((ext_vector_type(8)));
typedef float  f32x4_t  __attribute__((ext_vector_type(4)));
typedef short  short8_t __attribute__((ext_vector_type(8)));
typedef short  short4_t __attribute__((ext_vector_type(4)));

#define NB   4
#define NH   16
#define SEQ  2048
#define HD   64
#define BQ   64
#define BKV  64
#define LSTR 72   // LDS row stride in bf16 elems: 144B rows, 16B-aligned blocks

// masked score in base-2 domain: WHERE_CONST * log2(e)
#define MASK2 (-14426.950408889634f)

// uniform swizzled LDS address (shorts): row*72 + ((blk ^ (row>>3)) & 7) * 8
__device__ __forceinline__ int swz(int rowi, int blk) {
    return rowi * LSTR + (((blk) ^ (rowi >> 3)) & 7) * 8;
}

__global__ void __launch_bounds__(256)
fa_fwd(const float* __restrict__ qg,
       const float* __restrict__ kg,
       const float* __restrict__ vg,
       float* __restrict__ outg) {
    __shared__ alignas(16) short k_lds[BKV * LSTR];   // K tile bf16 [kv][d], block-swizzled
    __shared__ alignas(16) short vt_lds[HD * LSTR];   // V^T tile bf16 [d][kv], block-swizzled
    __shared__ alignas(16) short p_lds[BQ * LSTR];    // P bf16 [q][kv], block-swizzled

    const int tid  = threadIdx.x;
    const int wave = tid >> 6;
    const int lane = tid & 63;
    const int l16  = lane & 15;
    const int quad = lane >> 4;

    const int qt = (int)gridDim.x - 1 - (int)blockIdx.x;   // heavy blocks first
    const int bh = blockIdx.y;
    const int q0 = qt * BQ;

    const size_t base = (size_t)bh * SEQ * HD;
    const float* qp = qg + base;
    const float* kp = kg + base;
    const float* vp = vg + base;

    // ---- Q A-fragments (bf16): A[m=l16][k=quad*8+j] and [32+quad*8+j] ----
    bf16x8_t qf0, qf1;
    {
        const float* qr = qp + (size_t)(q0 + wave * 16 + l16) * HD;
        #pragma unroll
        for (int j = 0; j < 8; ++j) {
            qf0[j] = (__bf16)qr[quad * 8 + j];
            qf1[j] = (__bf16)qr[32 + quad * 8 + j];
        }
    }

    f32x4_t o_acc[4];
    const f32x4_t zero4 = {0.0f, 0.0f, 0.0f, 0.0f};
    #pragma unroll
    for (int c = 0; c < 4; ++c) o_acc[c] = zero4;
    float m_r[4], l_r[4];
    #pragma unroll
    for (int r = 0; r < 4; ++r) { m_r[r] = MASK2; l_r[r] = 0.0f; }

    const float SCL2 = 0.125f * 1.44269504088896340736f;  // scale * log2(e)

    const int ntiles = qt + 1;
    for (int t = 0; t < ntiles; ++t) {
        const int kt0 = t * BKV;
        __syncthreads();   // previous iteration's LDS readers done

        // ---- stage K [kv][d] and V^T [d][kv] as bf16 (fp32 global reads) ----
        #pragma unroll
        for (int it = 0; it < 4; ++it) {
            int idx = it * 256 + tid;       // 0..1023 = 64 rows x 16 float4-blocks
            int r0  = idx >> 4;
            int cb  = idx & 15;
            int d0  = cb * 4;
            f32x4_t k4 = *(const f32x4_t*)(kp + (size_t)(kt0 + r0) * HD + d0);
            f32x4_t v4 = *(const f32x4_t*)(vp + (size_t)(kt0 + r0) * HD + d0);
            // K: 4 consecutive d stay inside one 8-block -> one 8B write
            short4_t kw;
            #pragma unroll
            for (int j = 0; j < 4; ++j) kw[j] = __builtin_bit_cast(short, (__bf16)k4[j]);
            *(short4_t*)&k_lds[swz(r0, cb >> 1) + (d0 & 7)] = kw;
            // V^T: 4 scalar b16 writes (transpose)
            #pragma unroll
            for (int j = 0; j < 4; ++j) {
                int d = d0 + j;
                vt_lds[swz(d, r0 >> 3) + (r0 & 7)] = __builtin_bit_cast(short, (__bf16)v4[j]);
            }
        }
        __syncthreads();

        // ---- S = Q K^T  (D[m=q][n=kv]) ----
        f32x4_t s_acc[4];
        #pragma unroll
        for (int c = 0; c < 4; ++c) s_acc[c] = zero4;
        #pragma unroll
        for (int c = 0; c < 4; ++c) {
            const int kvrow = c * 16 + l16;
            bf16x8_t b0 = __builtin_bit_cast(bf16x8_t, *(const short8_t*)&k_lds[swz(kvrow, quad)]);
            bf16x8_t b1 = __builtin_bit_cast(bf16x8_t, *(const short8_t*)&k_lds[swz(kvrow, quad + 4)]);
            s_acc[c] = __builtin_amdgcn_mfma_f32_16x16x32_bf16(qf0, b0, s_acc[c], 0, 0, 0);
            s_acc[c] = __builtin_amdgcn_mfma_f32_16x16x32_bf16(qf1, b1, s_acc[c], 0, 0, 0);
        }

        // ---- online softmax (C layout: row = quad*4+r, col = c*16+l16) ----
        float sv[4][4];
        float vmax[4] = {MASK2, MASK2, MASK2, MASK2};
        const bool diag = (kt0 == q0);
        #pragma unroll
        for (int c = 0; c < 4; ++c) {
            #pragma unroll
            for (int r = 0; r < 4; ++r) {
                float x = s_acc[c][r] * SCL2;
                if (diag) {
                    int col = c * 16 + l16;
                    int row = wave * 16 + quad * 4 + r;
                    if (col > row) x = MASK2;
                }
                sv[c][r] = x;
                vmax[r] = fmaxf(vmax[r], x);
            }
        }
        #pragma unroll
        for (int r = 0; r < 4; ++r) {
            vmax[r] = fmaxf(vmax[r], __shfl_xor(vmax[r], 1));
            vmax[r] = fmaxf(vmax[r], __shfl_xor(vmax[r], 2));
            vmax[r] = fmaxf(vmax[r], __shfl_xor(vmax[r], 4));
            vmax[r] = fmaxf(vmax[r], __shfl_xor(vmax[r], 8));
        }

        float alpha[4];
        #pragma unroll
        for (int r = 0; r < 4; ++r) {
            float mn = fmaxf(m_r[r], vmax[r]);
            alpha[r] = __builtin_amdgcn_exp2f(fminf(m_r[r] - mn, 0.0f));
            m_r[r] = mn;
            l_r[r] *= alpha[r];
        }
        #pragma unroll
        for (int c = 0; c < 4; ++c) {
            #pragma unroll
            for (int r = 0; r < 4; ++r)
                o_acc[c][r] *= alpha[r];
        }

        // ---- P = exp2(sv - m); row sums; write P to LDS (C layout, swizzled) ----
        float rs[4] = {0.0f, 0.0f, 0.0f, 0.0f};
        #pragma unroll
        for (int c = 0; c < 4; ++c) {
            #pragma unroll
            for (int r = 0; r < 4; ++r) {
                float p = __builtin_amdgcn_exp2f(fminf(sv[c][r] - m_r[r], 0.0f));
                rs[r] += p;
                int prow = wave * 16 + quad * 4 + r;
                p_lds[swz(prow, 2 * c + (l16 >> 3)) + (l16 & 7)] =
                    __builtin_bit_cast(short, (__bf16)p);
            }
        }
        #pragma unroll
        for (int r = 0; r < 4; ++r) {
            rs[r] += __shfl_xor(rs[r], 1);
            rs[r] += __shfl_xor(rs[r], 2);
            rs[r] += __shfl_xor(rs[r], 4);
            rs[r] += __shfl_xor(rs[r], 8);
            l_r[r] += rs[r];
        }

        __syncthreads();   // P visible (conservative; wave-private in fact)

        // ---- O += P V  (A = P[m=q][k=kv], B = V^T rows as B[k=kv][n=d]) ----
        const int prow = wave * 16 + l16;
        bf16x8_t pf0 = __builtin_bit_cast(bf16x8_t, *(const short8_t*)&p_lds[swz(prow, quad)]);
        bf16x8_t pf1 = __builtin_bit_cast(bf16x8_t, *(const short8_t*)&p_lds[swz(prow, quad + 4)]);
        #pragma unroll
        for (int c = 0; c < 4; ++c) {
            const int d = c * 16 + l16;
            bf16x8_t b0 = __builtin_bit_cast(bf16x8_t, *(const short8_t*)&vt_lds[swz(d, quad)]);
            bf16x8_t b1 = __builtin_bit_cast(bf16x8_t, *(const short8_t*)&vt_lds[swz(d, quad + 4)]);
            o_acc[c] = __builtin_amdgcn_mfma_f32_16x16x32_bf16(pf0, b0, o_acc[c], 0, 0, 0);
            o_acc[c] = __builtin_amdgcn_mfma_f32_16x16x32_bf16(pf1, b1, o_acc[c], 0, 0, 0);
        }
    }

    // ---- epilogue: O / l, fp32 store to out[b][q][h*64 + d] ----
    const int b = bh >> 4;
    const int h = bh & 15;
    #pragma unroll
    for (int r = 0; r < 4; ++r) {
        const int row = q0 + wave * 16 + quad * 4 + r;
        const float inv_l = 1.0f / fmaxf(l_r[r], 1e-30f);
        float* op = outg + ((size_t)b * SEQ + row) * (NH * HD) + h * HD;
        #pragma unroll
        for (int c = 0; c < 4; ++c) {
            float val = o_acc[c][r] * inv_l;
            unsigned bits = __builtin_bit_cast(unsigned, val);
            if ((bits & 0x7F800000u) == 0x7F800000u) val = 0.0f;  // scrub inf/NaN
            op[c * 16 + l16] = val;
        }
    }
}

extern "C" void kernel_launch(void* const* d_in, const int* in_sizes, int n_in,
                              void* d_out, int out_size, void* d_ws, size_t ws_size,
                              hipStream_t stream) {
    const float* q = (const float*)d_in[0];
    const float* k = (const float*)d_in[1];
    const float* v = (const float*)d_in[2];
    float* out = (float*)d_out;
    dim3 grid(SEQ / BQ, NB * NH);
    fa_fwd<<<grid, 256, 0, stream>>>(q, k, v, out);
}